// Round 1
// baseline (8270.089 us; speedup 1.0000x reference)
//
#include <hip/hip_runtime.h>
#include <math.h>

#define N_NODES 100000
#define DIM 64
#define E_EDGES 1600000
#define BLOCKS_PER_ADJ (E_EDGES / 256)   // 6250

// ---------------- GEMM: h = x @ W + b ----------------
// 16 rows per block, 256 threads = 4 groups of 64 lanes, each group does 4 rows.
__global__ __launch_bounds__(256) void gemm_kernel(
    const float* __restrict__ x, const float* __restrict__ W,
    const float* __restrict__ b, float* __restrict__ h) {
    __shared__ float Ws[DIM * DIM];   // W[k][d] at Ws[k*64+d]
    __shared__ float xs[16 * DIM];    // 16 staged x rows
    const int tid = threadIdx.x;
    const long row0 = (long)blockIdx.x * 16;

    #pragma unroll
    for (int i = tid; i < DIM * DIM; i += 256) Ws[i] = W[i];
    #pragma unroll
    for (int i = tid; i < 16 * DIM; i += 256) xs[i] = x[row0 * DIM + i];
    __syncthreads();

    const int lane = tid & 63;
    const int grp  = tid >> 6;
    const float bias = b[lane];
    #pragma unroll
    for (int rr = 0; rr < 4; ++rr) {
        const int r = grp * 4 + rr;
        float acc = bias;
        #pragma unroll
        for (int k = 0; k < DIM; ++k)
            acc += xs[r * DIM + k] * Ws[k * DIM + lane];
        h[(row0 + r) * DIM + lane] = acc;
    }
}

// ---------------- SpMM scatter (one fused 2-adjacency op) ----------------
// Block handles 256 edges of one adjacency. Stage (r,c,v) in LDS, then
// 16 threads per edge: float4 gather from src[c], 4 atomicAdds into dst[r].
__global__ __launch_bounds__(256) void scatter_kernel(
    const float* __restrict__ src, float* __restrict__ dst,
    const int* __restrict__ rows, const int* __restrict__ cols,
    const float* __restrict__ vals, const int* __restrict__ idxes,
    float scale) {
    __shared__ int   lr[256];
    __shared__ int   lc[256];
    __shared__ float lv[256];
    const int tid  = threadIdx.x;
    const int slot = blockIdx.x / BLOCKS_PER_ADJ;          // 0 or 1
    const int eo   = (blockIdx.x % BLOCKS_PER_ADJ) * 256 + tid;
    const long base = (long)idxes[slot] * E_EDGES;
    lr[tid] = rows[base + eo];
    lc[tid] = cols[base + eo];
    lv[tid] = vals[base + eo] * scale;
    __syncthreads();

    const int sub = (tid & 15) * 4;   // column offset (0,4,...,60)
    const int e0  = tid >> 4;         // 0..15
    #pragma unroll
    for (int j = 0; j < 16; ++j) {
        const int s = j * 16 + e0;
        const int c = lc[s];
        const int r = lr[s];
        const float v = lv[s];
        const float4 hv = *(const float4*)(src + (long)c * DIM + sub);
        float* dp = dst + (long)r * DIM + sub;
        atomicAdd(dp + 0, v * hv.x);
        atomicAdd(dp + 1, v * hv.y);
        atomicAdd(dp + 2, v * hv.z);
        atomicAdd(dp + 3, v * hv.w);
    }
}

// ---------------- LayerNorm + exact GELU, in place ----------------
__global__ __launch_bounds__(256) void ln_gelu_kernel(
    float* __restrict__ io, const float* __restrict__ gamma,
    const float* __restrict__ beta) {
    const int tid  = threadIdx.x;
    const int lane = tid & 63;
    const int grp  = tid >> 6;
    const long row = (long)blockIdx.x * 4 + grp;
    const float v = io[row * DIM + lane];
    float s = v, s2 = v * v;
    #pragma unroll
    for (int off = 32; off > 0; off >>= 1) {
        s  += __shfl_xor(s, off);
        s2 += __shfl_xor(s2, off);
    }
    const float mu  = s * (1.0f / DIM);
    const float var = s2 * (1.0f / DIM) - mu * mu;
    const float inv = rsqrtf(var + 1e-5f);
    const float y = (v - mu) * inv * gamma[lane] + beta[lane];
    const float g = 0.5f * y * (1.0f + erff(y * 0.70710678118654752f));
    io[row * DIM + lane] = g;
}

extern "C" void kernel_launch(void* const* d_in, const int* in_sizes, int n_in,
                              void* d_out, int out_size, void* d_ws, size_t ws_size,
                              hipStream_t stream) {
    const float* x     = (const float*)d_in[0];
    const float* W     = (const float*)d_in[1];
    const float* b     = (const float*)d_in[2];
    const int*   rows  = (const int*)d_in[3];
    const int*   cols  = (const int*)d_in[4];
    const float* vals  = (const float*)d_in[5];
    const float* gamma = (const float*)d_in[6];
    const float* beta  = (const float*)d_in[7];
    const int*   idxes_seq = (const int*)d_in[8];   // [2,2]
    const int*   idxes_res = (const int*)d_in[9];   // [1,2]
    float* out = (float*)d_out;

    float* s0 = (float*)d_ws;                       // 25.6 MB
    float* s1 = s0 + (size_t)N_NODES * DIM;         // 25.6 MB
    const size_t rowbytes = (size_t)N_NODES * DIM * sizeof(float);

    hipMemsetAsync(s1, 0, rowbytes, stream);
    hipMemsetAsync(out, 0, rowbytes, stream);

    // s0 = x @ W + b
    gemm_kernel<<<N_NODES / 16, 256, 0, stream>>>(x, W, b, s0);
    // s1 = 0.5 * (A[i0] + A[i1]) @ s0
    scatter_kernel<<<2 * BLOCKS_PER_ADJ, 256, 0, stream>>>(
        s0, s1, rows, cols, vals, idxes_seq, 0.5f);
    // out = 0.5*(A[i2]+A[i3]) @ s1  +  0.5*(A[r0]+A[r1]) @ s0
    scatter_kernel<<<2 * BLOCKS_PER_ADJ, 256, 0, stream>>>(
        s1, out, rows, cols, vals, idxes_seq + 2, 0.5f);
    scatter_kernel<<<2 * BLOCKS_PER_ADJ, 256, 0, stream>>>(
        s0, out, rows, cols, vals, idxes_res, 0.5f);
    // out = gelu(layernorm(out))
    ln_gelu_kernel<<<N_NODES / 4, 256, 0, stream>>>(out, gamma, beta);
}

// Round 2
// 1114.627 us; speedup vs baseline: 7.4196x; 7.4196x over previous
//
#include <hip/hip_runtime.h>
#include <math.h>

#define N_NODES 100000
#define DIM 64
#define E_EDGES 1600000
#define N_ADJ 4
#define SCAN_TOT (N_ADJ * N_NODES)          // 400000
#define SCAN_EPB 1024                        // elems per scan block
#define SCAN_NBLK ((SCAN_TOT + SCAN_EPB - 1) / SCAN_EPB)  // 391

// ---------------- GEMM: s0 = x @ W + b ----------------
__global__ __launch_bounds__(256) void gemm_kernel(
    const float* __restrict__ x, const float* __restrict__ W,
    const float* __restrict__ b, float* __restrict__ h) {
    __shared__ float Ws[DIM * DIM];
    __shared__ float xs[16 * DIM];
    const int tid = threadIdx.x;
    const long row0 = (long)blockIdx.x * 16;
    for (int i = tid; i < DIM * DIM; i += 256) Ws[i] = W[i];
    for (int i = tid; i < 16 * DIM; i += 256) xs[i] = x[row0 * DIM + i];
    __syncthreads();
    const int lane = tid & 63;
    const int grp  = tid >> 6;
    const float bias = b[lane];
    #pragma unroll
    for (int rr = 0; rr < 4; ++rr) {
        const int r = grp * 4 + rr;
        float acc = bias;
        #pragma unroll
        for (int k = 0; k < DIM; ++k)
            acc += xs[r * DIM + k] * Ws[k * DIM + lane];
        h[(row0 + r) * DIM + lane] = acc;
    }
}

// ---------------- CSR build ----------------
__global__ __launch_bounds__(256) void hist_kernel(
    const int* __restrict__ rows, int* __restrict__ cnt) {
    const int a = blockIdx.y;
    const long e = (long)blockIdx.x * 256 + threadIdx.x;
    atomicAdd(&cnt[a * N_NODES + rows[(long)a * E_EDGES + e]], 1);
}

__global__ __launch_bounds__(256) void scan1_kernel(
    const int* __restrict__ cnt, int* __restrict__ rowptr, int* __restrict__ bs) {
    __shared__ int wtot[4];
    const int t = threadIdx.x;
    const int base = blockIdx.x * SCAN_EPB + t * 4;
    const int v0 = (base + 0 < SCAN_TOT) ? cnt[base + 0] : 0;
    const int v1 = (base + 1 < SCAN_TOT) ? cnt[base + 1] : 0;
    const int v2 = (base + 2 < SCAN_TOT) ? cnt[base + 2] : 0;
    const int v3 = (base + 3 < SCAN_TOT) ? cnt[base + 3] : 0;
    const int tsum = v0 + v1 + v2 + v3;
    const int lane = t & 63, wave = t >> 6;
    int incl = tsum;
    #pragma unroll
    for (int off = 1; off < 64; off <<= 1) {
        int n = __shfl_up(incl, off);
        if (lane >= off) incl += n;
    }
    if (lane == 63) wtot[wave] = incl;
    __syncthreads();
    int woff = 0;
    for (int w = 0; w < wave; ++w) woff += wtot[w];
    incl += woff;
    const int excl = incl - tsum;
    if (base + 0 < SCAN_TOT) rowptr[base + 0] = excl;
    if (base + 1 < SCAN_TOT) rowptr[base + 1] = excl + v0;
    if (base + 2 < SCAN_TOT) rowptr[base + 2] = excl + v0 + v1;
    if (base + 3 < SCAN_TOT) rowptr[base + 3] = excl + v0 + v1 + v2;
    if (t == 255) bs[blockIdx.x] = incl;
}

__global__ __launch_bounds__(512) void scan2_kernel(int* __restrict__ bs) {
    __shared__ int wtot[8];
    const int t = threadIdx.x;
    const int v = (t < SCAN_NBLK) ? bs[t] : 0;
    const int lane = t & 63, wave = t >> 6;
    int incl = v;
    #pragma unroll
    for (int off = 1; off < 64; off <<= 1) {
        int n = __shfl_up(incl, off);
        if (lane >= off) incl += n;
    }
    if (lane == 63) wtot[wave] = incl;
    __syncthreads();
    int woff = 0;
    for (int w = 0; w < wave; ++w) woff += wtot[w];
    incl += woff;
    if (t < SCAN_NBLK) bs[t] = incl - v;   // exclusive
}

__global__ __launch_bounds__(256) void scan3_kernel(
    int* __restrict__ rowptr, int* __restrict__ cursor, const int* __restrict__ bs) {
    const int i = blockIdx.x * 256 + threadIdx.x;
    if (i < SCAN_TOT) {
        const int r = rowptr[i] + bs[i >> 10];
        rowptr[i] = r;
        cursor[i] = r;
    }
    if (i == 0) rowptr[SCAN_TOT] = N_ADJ * E_EDGES;
}

__global__ __launch_bounds__(256) void place_kernel(
    const int* __restrict__ rows, const int* __restrict__ cols,
    const float* __restrict__ vals, int* __restrict__ cursor,
    int2* __restrict__ csr) {
    const int a = blockIdx.y;
    const long i = (long)a * E_EDGES + (long)blockIdx.x * 256 + threadIdx.x;
    const int r = rows[i];
    const int slot = atomicAdd(&cursor[a * N_NODES + r], 1);
    csr[slot] = make_int2(cols[i], __float_as_int(vals[i]));
}

// ---------------- Gather SpMM ----------------
// One wave per row; lane = output dim. Sums edges of 2 adjacency segments.
__device__ __forceinline__ float gather_segs(
    const float* __restrict__ src, const int2* __restrict__ csr,
    const int* __restrict__ rowptr, const int* __restrict__ idx,
    int row, int lane) {
    float acc = 0.0f;
    #pragma unroll
    for (int s = 0; s < 2; ++s) {
        const int a  = idx[s];
        const int p0 = rowptr[a * N_NODES + row];
        const int p1 = rowptr[a * N_NODES + row + 1];
        for (int j0 = p0; j0 < p1; j0 += 64) {
            const int nj = min(64, p1 - j0);
            int2 e = make_int2(0, 0);
            if (lane < nj) e = csr[j0 + lane];
            int j = 0;
            for (; j + 4 <= nj; j += 4) {
                const int   c0 = __shfl(e.x, j + 0);
                const int   c1 = __shfl(e.x, j + 1);
                const int   c2 = __shfl(e.x, j + 2);
                const int   c3 = __shfl(e.x, j + 3);
                const float v0 = __int_as_float(__shfl(e.y, j + 0));
                const float v1 = __int_as_float(__shfl(e.y, j + 1));
                const float v2 = __int_as_float(__shfl(e.y, j + 2));
                const float v3 = __int_as_float(__shfl(e.y, j + 3));
                const float x0 = src[(long)c0 * DIM + lane];
                const float x1 = src[(long)c1 * DIM + lane];
                const float x2 = src[(long)c2 * DIM + lane];
                const float x3 = src[(long)c3 * DIM + lane];
                acc = fmaf(v0, x0, acc);
                acc = fmaf(v1, x1, acc);
                acc = fmaf(v2, x2, acc);
                acc = fmaf(v3, x3, acc);
            }
            for (; j < nj; ++j) {
                const int   c = __shfl(e.x, j);
                const float v = __int_as_float(__shfl(e.y, j));
                acc = fmaf(v, src[(long)c * DIM + lane], acc);
            }
        }
    }
    return acc;
}

__global__ __launch_bounds__(256) void gather_op_kernel(
    const float* __restrict__ src, float* __restrict__ dst,
    const int2* __restrict__ csr, const int* __restrict__ rowptr,
    const int* __restrict__ idx) {
    const int lane = threadIdx.x & 63;
    const int row  = blockIdx.x * 4 + (threadIdx.x >> 6);
    const float acc = gather_segs(src, csr, rowptr, idx, row, lane);
    dst[(long)row * DIM + lane] = 0.5f * acc;
}

// Fused: out = gelu(LN(0.5*gather(s1, idx_seq1) + 0.5*gather(s0, idx_res)))
__global__ __launch_bounds__(256) void fused_op_ln_gelu_kernel(
    const float* __restrict__ s1, const float* __restrict__ s0,
    float* __restrict__ out, const int2* __restrict__ csr,
    const int* __restrict__ rowptr, const int* __restrict__ idx_seq1,
    const int* __restrict__ idx_res, const float* __restrict__ gamma,
    const float* __restrict__ beta) {
    const int lane = threadIdx.x & 63;
    const int row  = blockIdx.x * 4 + (threadIdx.x >> 6);
    const float a1 = gather_segs(s1, csr, rowptr, idx_seq1, row, lane);
    const float a0 = gather_segs(s0, csr, rowptr, idx_res,  row, lane);
    const float t = 0.5f * a1 + 0.5f * a0;
    float s = t, s2 = t * t;
    #pragma unroll
    for (int off = 32; off > 0; off >>= 1) {
        s  += __shfl_xor(s, off);
        s2 += __shfl_xor(s2, off);
    }
    const float mu  = s * (1.0f / DIM);
    const float var = s2 * (1.0f / DIM) - mu * mu;
    const float inv = rsqrtf(var + 1e-5f);
    const float y = (t - mu) * inv * gamma[lane] + beta[lane];
    const float g = 0.5f * y * (1.0f + erff(y * 0.70710678118654752f));
    out[(long)row * DIM + lane] = g;
}

extern "C" void kernel_launch(void* const* d_in, const int* in_sizes, int n_in,
                              void* d_out, int out_size, void* d_ws, size_t ws_size,
                              hipStream_t stream) {
    const float* x     = (const float*)d_in[0];
    const float* W     = (const float*)d_in[1];
    const float* b     = (const float*)d_in[2];
    const int*   rows  = (const int*)d_in[3];
    const int*   cols  = (const int*)d_in[4];
    const float* vals  = (const float*)d_in[5];
    const float* gamma = (const float*)d_in[6];
    const float* beta  = (const float*)d_in[7];
    const int*   idxes_seq = (const int*)d_in[8];   // [2,2] flat
    const int*   idxes_res = (const int*)d_in[9];   // [1,2] flat
    float* out = (float*)d_out;

    // workspace layout (csr first for 8B alignment)
    int2*  csr    = (int2*)d_ws;                        // 4E int2  = 51.2 MB
    float* s0     = (float*)(csr + (size_t)N_ADJ * E_EDGES);
    float* s1     = s0 + (size_t)N_NODES * DIM;
    int*   rowptr = (int*)(s1 + (size_t)N_NODES * DIM); // 4N+1 (+pad)
    int*   cursor = rowptr + SCAN_TOT + 2;              // 4N
    int*   bs     = cursor + SCAN_TOT;                  // SCAN_NBLK

    hipMemsetAsync(cursor, 0, (size_t)SCAN_TOT * sizeof(int), stream);

    gemm_kernel<<<N_NODES / 16, 256, 0, stream>>>(x, W, b, s0);

    dim3 egrid(E_EDGES / 256, N_ADJ);
    hist_kernel <<<egrid, 256, 0, stream>>>(rows, cursor);
    scan1_kernel<<<SCAN_NBLK, 256, 0, stream>>>(cursor, rowptr, bs);
    scan2_kernel<<<1, 512, 0, stream>>>(bs);
    scan3_kernel<<<(SCAN_TOT + 255) / 256, 256, 0, stream>>>(rowptr, cursor, bs);
    place_kernel<<<egrid, 256, 0, stream>>>(rows, cols, vals, cursor, csr);

    // s1 = 0.5*(A[i0]+A[i1]) @ s0
    gather_op_kernel<<<N_NODES / 4, 256, 0, stream>>>(s0, s1, csr, rowptr, idxes_seq);
    // out = gelu(LN(0.5*(A[i2]+A[i3])@s1 + 0.5*(A[r0]+A[r1])@s0))
    fused_op_ln_gelu_kernel<<<N_NODES / 4, 256, 0, stream>>>(
        s1, s0, out, csr, rowptr, idxes_seq + 2, idxes_res, gamma, beta);
}